// Round 3
// baseline (203.632 us; speedup 1.0000x reference)
//
#include <hip/hip_runtime.h>

constexpr int Fdim = 2000;
constexpr int Wdim = 4000;
constexpr int Edim = 16;
constexpr int Hdim = 64;
constexpr int Bdim = 256;
constexpr int FTILE = 4;      // f-rows per block in main kernel
constexpr int WCHUNKS = 8;    // w-split per f-tile (occupancy)
constexpr int WCHUNK = Wdim / WCHUNKS;  // 500
constexpr float kLog2e = 1.4426950408889634f;

__device__ __forceinline__ float fast_exp2(float x) {
#if __has_builtin(__builtin_amdgcn_exp2f)
  return __builtin_amdgcn_exp2f(x);
#else
  return exp2f(x);
#endif
}
__device__ __forceinline__ float fast_rcp(float x) {
#if __has_builtin(__builtin_amdgcn_rcpf)
  return __builtin_amdgcn_rcpf(x);
#else
  return 1.0f / x;
#endif
}
__device__ __forceinline__ float4 f4_fma_s(float s, float4 a, float4 b) {
  return make_float4(fmaf(s, a.x, b.x), fmaf(s, a.y, b.y),
                     fmaf(s, a.z, b.z), fmaf(s, a.w, b.w));
}

// --- detect whether mask is 1-byte bool or 4-byte int32 -------------------
// bool layout: random 0/1 bytes everywhere -> bytes at i%4!=0 are ~50% ones.
// int32 layout (values 0/1 little-endian): bytes at i%4!=0 are ALL zero.
__global__ void detect_mask_kernel(const unsigned char* __restrict__ mask,
                                   int* __restrict__ flag) {
  __shared__ int any;
  if (threadIdx.x == 0) any = 0;
  __syncthreads();
  int acc = 0;
  for (int i = threadIdx.x; i < 8192; i += 256)
    if ((i & 3) != 0) acc |= mask[i];
  if (acc) atomicOr(&any, 1);
  __syncthreads();
  if (threadIdx.x == 0) *flag = (any != 0) ? 1 : 0;  // 1 = byte layout
}

// --- prep:
//   efp[f][h] = exp2( (femb@Ww[:E] + b) * 2log2e )   (so efp*ehp = e^{2x})
//   ehp[h][w] = exp2( (hemb@Ww[E:])    * 2log2e )
//   wusum = sum(Wu)
__global__ __launch_bounds__(256) void prep_kernel(
    const float* __restrict__ femb, const float* __restrict__ hemb,
    const float* __restrict__ Ww, const float* __restrict__ bw,
    const float* __restrict__ Wu,
    float* __restrict__ efp, float* __restrict__ ehp,
    float* __restrict__ wusum) {
  constexpr float S = 2.0f * kLog2e;
  constexpr int NF = Fdim * Hdim;   // 128000
  constexpr int NH = Hdim * Wdim;   // 256000
  int idx = blockIdx.x * 256 + threadIdx.x;
  if (idx < NF) {
    int f = idx >> 6, h = idx & 63;
    float acc = bw[h];
#pragma unroll
    for (int e = 0; e < Edim; ++e)
      acc = fmaf(femb[f * Edim + e], Ww[e * Hdim + h], acc);
    efp[idx] = fast_exp2(acc * S);
  } else if (idx < NF + NH) {
    int j = idx - NF;
    int h = j / Wdim, w = j - h * Wdim;
    float acc = 0.f;
#pragma unroll
    for (int e = 0; e < Edim; ++e)
      acc = fmaf(hemb[w * Edim + e], Ww[(Edim + e) * Hdim + h], acc);
    ehp[j] = fast_exp2(acc * S);
  } else if (idx < NF + NH + 64) {
    int l = idx - (NF + NH);        // lanes 0..63 of last block's wave 0
    float s = Wu[l];
#pragma unroll
    for (int o = 32; o > 0; o >>= 1) s += __shfl_down(s, o, 64);
    if (l == 0) *wusum = s;
  }
}

// --- main: block = (f-tile = blockIdx.x, w-chunk = blockIdx.y).
// tanh(x) = 1 - 2/(1+e^{2x});  e^{2x} = efp[f][h]*ehp[h][w]  (no exp in loop!)
// sneg = sum_h 2*Wu[h] * rcp(1 + efp*ehp);  score = wusum - sneg
// sc = mask ? exp(score) : 0
// partials: part[(f*WCHUNKS+chunk)*17 + {e | 16}] = {num_e | den}
__global__ __launch_bounds__(256) void attn_ctx_kernel(
    const float* __restrict__ efp, const float* __restrict__ ehp,
    const float* __restrict__ Wu, const float* __restrict__ wusum_p,
    const unsigned char* mask_b, const int* __restrict__ mflag,
    const float* __restrict__ hemb, float* __restrict__ part) {
  const int f0 = blockIdx.x * FTILE;
  const int chunk = blockIdx.y;
  const int tid = threadIdx.x;

  __shared__ float4 s_fp[Hdim];          // packed efp for the 4 f's
  __shared__ float s_wu[Hdim];           // 2*Wu[h]
  __shared__ float s_red[4][FTILE][20];  // [wave][fi][16 num + den@16] (80B rows, 16B-aligned)

  if (tid < Hdim) {
    s_wu[tid] = 2.0f * Wu[tid];
    float a = efp[(f0 + 0) * Hdim + tid];
    float b = efp[(f0 + 1) * Hdim + tid];
    float c = efp[(f0 + 2) * Hdim + tid];
    float d = efp[(f0 + 3) * Hdim + tid];
    s_fp[tid] = make_float4(a, b, c, d);
  }
  __syncthreads();

  const int mbyte = *mflag;
  const float wls = (*wusum_p) * kLog2e;  // wusum * log2e
  const int* mask_i = (const int*)mask_b;

  float den[FTILE] = {0.f, 0.f, 0.f, 0.f};
  float4 cacc[FTILE][4];
#pragma unroll
  for (int fi = 0; fi < FTILE; ++fi)
#pragma unroll
    for (int q = 0; q < 4; ++q) cacc[fi][q] = make_float4(0.f, 0.f, 0.f, 0.f);

  const int wend = (chunk + 1) * WCHUNK;
  for (int w = chunk * WCHUNK + tid; w < wend; w += 256) {
    float4 sneg = make_float4(0.f, 0.f, 0.f, 0.f);
#pragma unroll 8
    for (int h = 0; h < Hdim; ++h) {
      float hp = ehp[h * Wdim + w];      // coalesced, L2-resident
      float4 fp = s_fp[h];               // LDS broadcast (ds_read_b128)
      float wu = s_wu[h];
      float4 u = make_float4(fp.x * hp, fp.y * hp, fp.z * hp, fp.w * hp);
      float4 d = make_float4(u.x + 1.f, u.y + 1.f, u.z + 1.f, u.w + 1.f);
      float4 r = make_float4(fast_rcp(d.x), fast_rcp(d.y),
                             fast_rcp(d.z), fast_rcp(d.w));
      sneg = f4_fma_s(wu, r, sneg);
    }
    const float4* hrow = (const float4*)(hemb + (size_t)w * Edim);
    float4 hr0 = hrow[0], hr1 = hrow[1], hr2 = hrow[2], hr3 = hrow[3];
    float snegs[4] = {sneg.x, sneg.y, sneg.z, sneg.w};
#pragma unroll
    for (int fi = 0; fi < FTILE; ++fi) {
      const int midx = (f0 + fi) * Wdim + w;
      bool m = mbyte ? (mask_b[midx] != 0) : (mask_i[midx] != 0);
      float sc = m ? fast_exp2(fmaf(snegs[fi], -kLog2e, wls)) : 0.0f;
      den[fi] += sc;
      cacc[fi][0] = f4_fma_s(sc, hr0, cacc[fi][0]);
      cacc[fi][1] = f4_fma_s(sc, hr1, cacc[fi][1]);
      cacc[fi][2] = f4_fma_s(sc, hr2, cacc[fi][2]);
      cacc[fi][3] = f4_fma_s(sc, hr3, cacc[fi][3]);
    }
  }

  // block reduction: wave shuffle -> LDS -> partial write
  const int lane = tid & 63, wv = tid >> 6;
#pragma unroll
  for (int fi = 0; fi < FTILE; ++fi) {
    float v = den[fi];
#pragma unroll
    for (int o = 32; o > 0; o >>= 1) v += __shfl_down(v, o, 64);
    if (lane == 0) s_red[wv][fi][16] = v;
#pragma unroll
    for (int q = 0; q < 4; ++q) {
      float4 cv = cacc[fi][q];
#pragma unroll
      for (int o = 32; o > 0; o >>= 1) {
        cv.x += __shfl_down(cv.x, o, 64);
        cv.y += __shfl_down(cv.y, o, 64);
        cv.z += __shfl_down(cv.z, o, 64);
        cv.w += __shfl_down(cv.w, o, 64);
      }
      if (lane == 0) *(float4*)&s_red[wv][fi][4 * q] = cv;
    }
  }
  __syncthreads();
  if (tid < FTILE * 17) {
    int fi = tid / 17, k = tid % 17;
    int kk = (k == 16) ? 16 : k;
    float tot = s_red[0][fi][kk] + s_red[1][fi][kk] + s_red[2][fi][kk] +
                s_red[3][fi][kk];
    part[((f0 + fi) * WCHUNKS + chunk) * 17 + k] = tot;
  }
}

// --- finalize: ctx[f][e] = sum_c num / sum_c den ---------------------------
__global__ __launch_bounds__(256) void finalize_kernel(
    const float* __restrict__ part, float* __restrict__ ctx) {
  int idx = blockIdx.x * 256 + threadIdx.x;
  if (idx >= Fdim * Edim) return;
  int f = idx >> 4, e = idx & 15;
  const float* p = part + f * WCHUNKS * 17;
  float den = 0.f, num = 0.f;
#pragma unroll
  for (int c = 0; c < WCHUNKS; ++c) {
    den += p[c * 17 + 16];
    num += p[c * 17 + e];
  }
  ctx[idx] = num / den;
}

// --- out[b][e] = sum_f values[b][f] * ctx[f][e] ----------------------------
__global__ __launch_bounds__(256) void out_gemv_kernel(
    const float* __restrict__ values, const float* __restrict__ ctx,
    float* __restrict__ out) {
  const int b = blockIdx.x, tid = threadIdx.x;
  float acc[Edim];
#pragma unroll
  for (int e = 0; e < Edim; ++e) acc[e] = 0.f;
  for (int f = tid; f < Fdim; f += 256) {
    float v = values[b * Fdim + f];
    const float4* c4 = (const float4*)(ctx + f * Edim);
    float4 c0 = c4[0], c1 = c4[1], c2 = c4[2], c3 = c4[3];
    float cr[Edim] = {c0.x, c0.y, c0.z, c0.w, c1.x, c1.y, c1.z, c1.w,
                      c2.x, c2.y, c2.z, c2.w, c3.x, c3.y, c3.z, c3.w};
#pragma unroll
    for (int e = 0; e < Edim; ++e) acc[e] = fmaf(v, cr[e], acc[e]);
  }
  __shared__ float s_red[4][Edim];
  const int lane = tid & 63, wv = tid >> 6;
#pragma unroll
  for (int e = 0; e < Edim; ++e) {
    float a = acc[e];
#pragma unroll
    for (int o = 32; o > 0; o >>= 1) a += __shfl_down(a, o, 64);
    if (lane == 0) s_red[wv][e] = a;
  }
  __syncthreads();
  if (tid < Edim)
    out[b * Edim + tid] =
        s_red[0][tid] + s_red[1][tid] + s_red[2][tid] + s_red[3][tid];
}

extern "C" void kernel_launch(void* const* d_in, const int* in_sizes, int n_in,
                              void* d_out, int out_size, void* d_ws,
                              size_t ws_size, hipStream_t stream) {
  const float* values = (const float*)d_in[0];
  const float* femb   = (const float*)d_in[1];
  const float* hemb   = (const float*)d_in[2];
  const float* Ww     = (const float*)d_in[3];
  const float* bw     = (const float*)d_in[4];
  const float* Wu     = (const float*)d_in[5];
  const unsigned char* mask = (const unsigned char*)d_in[6];
  float* out = (float*)d_out;

  // workspace layout (floats):
  // efp[F*H] | ehp[H*W] | ctx[F*E] | wusum | mflag | part[F*WCHUNKS*17]
  float* ws = (float*)d_ws;
  float* efp = ws;                                    // 128000
  float* ehp = efp + Fdim * Hdim;                     // 256000
  float* ctx = ehp + (size_t)Hdim * Wdim;             // 32000
  float* wusum = ctx + Fdim * Edim;                   // 1
  int* mflag = (int*)(wusum + 1);                     // 1
  float* part = (float*)(mflag + 1);                  // 2000*8*17 = 272000

  detect_mask_kernel<<<dim3(1), dim3(256), 0, stream>>>(mask, mflag);

  constexpr int prep_blocks = (Fdim * Hdim + Hdim * Wdim) / 256 + 1;  // 1501
  prep_kernel<<<dim3(prep_blocks), dim3(256), 0, stream>>>(
      femb, hemb, Ww, bw, Wu, efp, ehp, wusum);

  attn_ctx_kernel<<<dim3(Fdim / FTILE, WCHUNKS), dim3(256), 0, stream>>>(
      efp, ehp, Wu, wusum, mask, mflag, hemb, part);

  finalize_kernel<<<dim3((Fdim * Edim + 255) / 256), dim3(256), 0, stream>>>(
      part, ctx);

  out_gemv_kernel<<<dim3(Bdim), dim3(256), 0, stream>>>(values, ctx, out);
}

// Round 4
// 110.849 us; speedup vs baseline: 1.8370x; 1.8370x over previous
//
#include <hip/hip_runtime.h>

constexpr int Fdim = 2000;
constexpr int Wdim = 4000;
constexpr int Edim = 16;
constexpr int Hdim = 64;
constexpr int Bdim = 256;
constexpr int FTILE = 4;      // f-rows per block in main kernel
constexpr int WCHUNKS = 4;    // w-split per f-tile
constexpr int WCHUNK = Wdim / WCHUNKS;  // 1000
constexpr int NW = 4;         // w's per thread (stride 256); 4*256=1024 >= 1000 -> tail guard
constexpr float kLog2e = 1.4426950408889634f;

__device__ __forceinline__ float fast_exp2(float x) {
#if __has_builtin(__builtin_amdgcn_exp2f)
  return __builtin_amdgcn_exp2f(x);
#else
  return exp2f(x);
#endif
}
__device__ __forceinline__ float fast_rcp(float x) {
#if __has_builtin(__builtin_amdgcn_rcpf)
  return __builtin_amdgcn_rcpf(x);
#else
  return 1.0f / x;
#endif
}
__device__ __forceinline__ float4 f4_fma_s(float s, float4 a, float4 b) {
  return make_float4(fmaf(s, a.x, b.x), fmaf(s, a.y, b.y),
                     fmaf(s, a.z, b.z), fmaf(s, a.w, b.w));
}

// ---- DPP wave-64 sum (VALU pipe; no ds_bpermute). Result valid in lane 63.
// Sequence: row_shr 1,2,3 (of original) -> 4-wide; row_shr:4 -> 8-wide;
// row_shr:8 -> row sums in lane 15 of each row; row_bcast:15, row_bcast:31.
// bound_ctrl=true => invalid-source lanes contribute 0.
template <int CTRL>
__device__ __forceinline__ float dpp_part(float x) {
  return __int_as_float(
      __builtin_amdgcn_update_dpp(0, __float_as_int(x), CTRL, 0xF, 0xF, true));
}
__device__ __forceinline__ float wave64_sum(float x) {
  const float x0 = x;
  x += dpp_part<0x111>(x0);  // row_shr:1
  x += dpp_part<0x112>(x0);  // row_shr:2
  x += dpp_part<0x113>(x0);  // row_shr:3
  x += dpp_part<0x114>(x);   // row_shr:4
  x += dpp_part<0x118>(x);   // row_shr:8
  x += dpp_part<0x142>(x);   // row_bcast:15
  x += dpp_part<0x143>(x);   // row_bcast:31
  return x;                  // lane 63 holds the full sum
}

// --- detect whether mask is 1-byte bool or 4-byte int32 -------------------
__global__ void detect_mask_kernel(const unsigned char* __restrict__ mask,
                                   int* __restrict__ flag) {
  __shared__ int any;
  if (threadIdx.x == 0) any = 0;
  __syncthreads();
  int acc = 0;
  for (int i = threadIdx.x; i < 8192; i += 256)
    if ((i & 3) != 0) acc |= mask[i];
  if (acc) atomicOr(&any, 1);
  __syncthreads();
  if (threadIdx.x == 0) *flag = (any != 0) ? 1 : 0;  // 1 = byte layout
}

// --- prep:
//   efp[f][h] = exp2( (femb@Ww[:E] + b) * 2log2e )   (so efp*ehp = e^{2x})
//   ehp[h][w] = exp2( (hemb@Ww[E:])    * 2log2e )
//   wusum = sum(Wu)
__global__ __launch_bounds__(256) void prep_kernel(
    const float* __restrict__ femb, const float* __restrict__ hemb,
    const float* __restrict__ Ww, const float* __restrict__ bw,
    const float* __restrict__ Wu,
    float* __restrict__ efp, float* __restrict__ ehp,
    float* __restrict__ wusum) {
  constexpr float S = 2.0f * kLog2e;
  constexpr int NF = Fdim * Hdim;   // 128000
  constexpr int NH = Hdim * Wdim;   // 256000
  int idx = blockIdx.x * 256 + threadIdx.x;
  if (idx < NF) {
    int f = idx >> 6, h = idx & 63;
    float acc = bw[h];
#pragma unroll
    for (int e = 0; e < Edim; ++e)
      acc = fmaf(femb[f * Edim + e], Ww[e * Hdim + h], acc);
    efp[idx] = fast_exp2(acc * S);
  } else if (idx < NF + NH) {
    int j = idx - NF;
    int h = j / Wdim, w = j - h * Wdim;
    float acc = 0.f;
#pragma unroll
    for (int e = 0; e < Edim; ++e)
      acc = fmaf(hemb[w * Edim + e], Ww[(Edim + e) * Hdim + h], acc);
    ehp[j] = fast_exp2(acc * S);
  } else if (idx < NF + NH + 64) {
    int l = idx - (NF + NH);
    float s = Wu[l];
#pragma unroll
    for (int o = 32; o > 0; o >>= 1) s += __shfl_down(s, o, 64);
    if (l == 0) *wusum = s;
  }
}

// --- main: block = (f-tile, w-chunk). Flipped loop nest: h outer, NW w's
// per thread held in registers. tanh(x) = 1 - 2/(1+e^{2x}), e^{2x}=efp*ehp.
// sneg[fi][j] = sum_h 2Wu[h]*rcp(fma(efp,ehp,1)); sc = m*exp2(wls-log2e*sneg)
__global__ __launch_bounds__(256, 3) void attn_ctx_kernel(
    const float* __restrict__ efp, const float* __restrict__ ehp,
    const float* __restrict__ Wu, const float* __restrict__ wusum_p,
    const unsigned char* mask_b, const int* __restrict__ mflag,
    const float* __restrict__ hemb, float* __restrict__ part) {
  const int f0 = blockIdx.x * FTILE;
  const int chunk = blockIdx.y;
  const int tid = threadIdx.x;

  __shared__ float4 s_fp[Hdim];          // efp packed for the 4 f's
  __shared__ float s_wu[Hdim];           // 2*Wu[h]
  __shared__ float s_red[4][FTILE][20];  // [wave][fi][16 num + den@16]

  if (tid < Hdim) {
    s_wu[tid] = 2.0f * Wu[tid];
    float a = efp[(f0 + 0) * Hdim + tid];
    float b = efp[(f0 + 1) * Hdim + tid];
    float c = efp[(f0 + 2) * Hdim + tid];
    float d = efp[(f0 + 3) * Hdim + tid];
    s_fp[tid] = make_float4(a, b, c, d);
  }
  __syncthreads();

  const int mbyte = *mflag;
  const float wls = (*wusum_p) * kLog2e;
  const int* mask_i = (const int*)mask_b;

  // per-thread w set: wbase + 256*j, guarded against chunk end
  const int wend = (chunk + 1) * WCHUNK;
  const int wbase = chunk * WCHUNK + tid;
  int wcl[NW];
  bool wok[NW];
#pragma unroll
  for (int j = 0; j < NW; ++j) {
    int w = wbase + 256 * j;
    wok[j] = (w < wend);
    wcl[j] = wok[j] ? w : (wend - 1);   // clamped (safe loads, zeroed later)
  }

  float sneg[FTILE][NW];
#pragma unroll
  for (int fi = 0; fi < FTILE; ++fi)
#pragma unroll
    for (int j = 0; j < NW; ++j) sneg[fi][j] = 0.f;

  // ---- h-outer main loop: 1 LDS b128 + 1 LDS b32 + NW global dwords per h
#pragma unroll 4
  for (int h = 0; h < Hdim; ++h) {
    const float* er = ehp + h * Wdim;
    float hp[NW];
#pragma unroll
    for (int j = 0; j < NW; ++j) hp[j] = er[wcl[j]];
    float4 fp4 = s_fp[h];
    float wu = s_wu[h];
    float fp[4] = {fp4.x, fp4.y, fp4.z, fp4.w};
#pragma unroll
    for (int j = 0; j < NW; ++j)
#pragma unroll
      for (int fi = 0; fi < FTILE; ++fi) {
        float d = fmaf(fp[fi], hp[j], 1.0f);          // 1 + e^{2x}
        sneg[fi][j] = fmaf(wu, fast_rcp(d), sneg[fi][j]);
      }
  }

  // ---- mask bits (uniform branch on layout), zeroed for invalid tail w's
  float mbit[FTILE][NW];
  if (mbyte) {
#pragma unroll
    for (int fi = 0; fi < FTILE; ++fi)
#pragma unroll
      for (int j = 0; j < NW; ++j)
        mbit[fi][j] = wok[j] ? (float)mask_b[(f0 + fi) * Wdim + wcl[j]] : 0.f;
  } else {
#pragma unroll
    for (int fi = 0; fi < FTILE; ++fi)
#pragma unroll
      for (int j = 0; j < NW; ++j)
        mbit[fi][j] = wok[j] ? (float)mask_i[(f0 + fi) * Wdim + wcl[j]] : 0.f;
  }

  // ---- score + context accumulation
  float den[FTILE] = {0.f, 0.f, 0.f, 0.f};
  float4 cacc[FTILE][4];
#pragma unroll
  for (int fi = 0; fi < FTILE; ++fi)
#pragma unroll
    for (int q = 0; q < 4; ++q) cacc[fi][q] = make_float4(0.f, 0.f, 0.f, 0.f);

#pragma unroll
  for (int j = 0; j < NW; ++j) {
    const float4* hrow = (const float4*)(hemb + (size_t)wcl[j] * Edim);
    float4 hr0 = hrow[0], hr1 = hrow[1], hr2 = hrow[2], hr3 = hrow[3];
#pragma unroll
    for (int fi = 0; fi < FTILE; ++fi) {
      float sc = fast_exp2(fmaf(sneg[fi][j], -kLog2e, wls)) * mbit[fi][j];
      den[fi] += sc;
      cacc[fi][0] = f4_fma_s(sc, hr0, cacc[fi][0]);
      cacc[fi][1] = f4_fma_s(sc, hr1, cacc[fi][1]);
      cacc[fi][2] = f4_fma_s(sc, hr2, cacc[fi][2]);
      cacc[fi][3] = f4_fma_s(sc, hr3, cacc[fi][3]);
    }
  }

  // ---- DPP in-wave reduction (VALU pipe), lane 63 -> LDS
  const int lane = tid & 63, wv = tid >> 6;
#pragma unroll
  for (int fi = 0; fi < FTILE; ++fi) {
    float d = wave64_sum(den[fi]);
    if (lane == 63) s_red[wv][fi][16] = d;
#pragma unroll
    for (int q = 0; q < 4; ++q) {
      float cx = wave64_sum(cacc[fi][q].x);
      float cy = wave64_sum(cacc[fi][q].y);
      float cz = wave64_sum(cacc[fi][q].z);
      float cw = wave64_sum(cacc[fi][q].w);
      if (lane == 63) {
        s_red[wv][fi][4 * q + 0] = cx;
        s_red[wv][fi][4 * q + 1] = cy;
        s_red[wv][fi][4 * q + 2] = cz;
        s_red[wv][fi][4 * q + 3] = cw;
      }
    }
  }
  __syncthreads();
  if (tid < FTILE * 17) {
    int fi = tid / 17, k = tid % 17;
    float tot = s_red[0][fi][k] + s_red[1][fi][k] + s_red[2][fi][k] +
                s_red[3][fi][k];
    part[((f0 + fi) * WCHUNKS + chunk) * 17 + k] = tot;
  }
}

// --- finalize: ctx[f][e] = sum_c num / sum_c den ---------------------------
__global__ __launch_bounds__(256) void finalize_kernel(
    const float* __restrict__ part, float* __restrict__ ctx) {
  int idx = blockIdx.x * 256 + threadIdx.x;
  if (idx >= Fdim * Edim) return;
  int f = idx >> 4, e = idx & 15;
  const float* p = part + f * WCHUNKS * 17;
  float den = 0.f, num = 0.f;
#pragma unroll
  for (int c = 0; c < WCHUNKS; ++c) {
    den += p[c * 17 + 16];
    num += p[c * 17 + e];
  }
  ctx[idx] = num / den;
}

// --- out[b][e] = sum_f values[b][f] * ctx[f][e] ----------------------------
__global__ __launch_bounds__(256) void out_gemv_kernel(
    const float* __restrict__ values, const float* __restrict__ ctx,
    float* __restrict__ out) {
  const int b = blockIdx.x, tid = threadIdx.x;
  float acc[Edim];
#pragma unroll
  for (int e = 0; e < Edim; ++e) acc[e] = 0.f;
  for (int f = tid; f < Fdim; f += 256) {
    float v = values[b * Fdim + f];
    const float4* c4 = (const float4*)(ctx + f * Edim);
    float4 c0 = c4[0], c1 = c4[1], c2 = c4[2], c3 = c4[3];
    float cr[Edim] = {c0.x, c0.y, c0.z, c0.w, c1.x, c1.y, c1.z, c1.w,
                      c2.x, c2.y, c2.z, c2.w, c3.x, c3.y, c3.z, c3.w};
#pragma unroll
    for (int e = 0; e < Edim; ++e) acc[e] = fmaf(v, cr[e], acc[e]);
  }
  __shared__ float s_red[4][Edim];
  const int lane = tid & 63, wv = tid >> 6;
#pragma unroll
  for (int e = 0; e < Edim; ++e) {
    float a = wave64_sum(acc[e]);
    if (lane == 63) s_red[wv][e] = a;
  }
  __syncthreads();
  if (tid < Edim)
    out[b * Edim + tid] =
        s_red[0][tid] + s_red[1][tid] + s_red[2][tid] + s_red[3][tid];
}

extern "C" void kernel_launch(void* const* d_in, const int* in_sizes, int n_in,
                              void* d_out, int out_size, void* d_ws,
                              size_t ws_size, hipStream_t stream) {
  const float* values = (const float*)d_in[0];
  const float* femb   = (const float*)d_in[1];
  const float* hemb   = (const float*)d_in[2];
  const float* Ww     = (const float*)d_in[3];
  const float* bw     = (const float*)d_in[4];
  const float* Wu     = (const float*)d_in[5];
  const unsigned char* mask = (const unsigned char*)d_in[6];
  float* out = (float*)d_out;

  // workspace (floats): efp[F*H] | ehp[H*W] | ctx[F*E] | wusum | mflag | part
  float* ws = (float*)d_ws;
  float* efp = ws;                                    // 128000
  float* ehp = efp + Fdim * Hdim;                     // 256000
  float* ctx = ehp + (size_t)Hdim * Wdim;             // 32000
  float* wusum = ctx + Fdim * Edim;                   // 1
  int* mflag = (int*)(wusum + 1);                     // 1
  float* part = (float*)(mflag + 1);                  // 2000*4*17 = 136000

  detect_mask_kernel<<<dim3(1), dim3(256), 0, stream>>>(mask, mflag);

  constexpr int prep_blocks = (Fdim * Hdim + Hdim * Wdim) / 256 + 1;  // 1501
  prep_kernel<<<dim3(prep_blocks), dim3(256), 0, stream>>>(
      femb, hemb, Ww, bw, Wu, efp, ehp, wusum);

  attn_ctx_kernel<<<dim3(Fdim / FTILE, WCHUNKS), dim3(256), 0, stream>>>(
      efp, ehp, Wu, wusum, mask, mflag, hemb, part);

  finalize_kernel<<<dim3((Fdim * Edim + 255) / 256), dim3(256), 0, stream>>>(
      part, ctx);

  out_gemv_kernel<<<dim3(Bdim), dim3(256), 0, stream>>>(values, ctx, out);
}

// Round 5
// 96.223 us; speedup vs baseline: 2.1163x; 1.1520x over previous
//
#include <hip/hip_runtime.h>

constexpr int Fdim = 2000;
constexpr int Wdim = 4000;
constexpr int Edim = 16;
constexpr int Hdim = 64;
constexpr int Bdim = 256;
constexpr int FTILE = 4;      // f-rows per block in main kernel
constexpr int WCHUNKS = 4;    // w-chunks (blockIdx.y)
constexpr int WTILE = 1024;   // w's per chunk (4*256); last chunk short (928)
constexpr int NW = 4;         // CONSECUTIVE w's per thread
constexpr float kLog2e = 1.4426950408889634f;

__device__ __forceinline__ float fast_exp2(float x) {
#if __has_builtin(__builtin_amdgcn_exp2f)
  return __builtin_amdgcn_exp2f(x);
#else
  return exp2f(x);
#endif
}
__device__ __forceinline__ float fast_rcp(float x) {
#if __has_builtin(__builtin_amdgcn_rcpf)
  return __builtin_amdgcn_rcpf(x);
#else
  return 1.0f / x;
#endif
}
__device__ __forceinline__ float4 f4_fma_s(float s, float4 a, float4 b) {
  return make_float4(fmaf(s, a.x, b.x), fmaf(s, a.y, b.y),
                     fmaf(s, a.z, b.z), fmaf(s, a.w, b.w));
}

// ---- DPP wave-64 sum (VALU pipe; no ds_bpermute). Result valid in lane 63.
template <int CTRL>
__device__ __forceinline__ float dpp_part(float x) {
  return __int_as_float(
      __builtin_amdgcn_update_dpp(0, __float_as_int(x), CTRL, 0xF, 0xF, true));
}
__device__ __forceinline__ float wave64_sum(float x) {
  const float x0 = x;
  x += dpp_part<0x111>(x0);  // row_shr:1
  x += dpp_part<0x112>(x0);  // row_shr:2
  x += dpp_part<0x113>(x0);  // row_shr:3
  x += dpp_part<0x114>(x);   // row_shr:4
  x += dpp_part<0x118>(x);   // row_shr:8
  x += dpp_part<0x142>(x);   // row_bcast:15
  x += dpp_part<0x143>(x);   // row_bcast:31
  return x;                  // lane 63 holds the full sum
}

// --- detect whether mask is 1-byte bool or 4-byte int32 -------------------
__global__ void detect_mask_kernel(const unsigned char* __restrict__ mask,
                                   int* __restrict__ flag) {
  __shared__ int any;
  if (threadIdx.x == 0) any = 0;
  __syncthreads();
  int acc = 0;
  for (int i = threadIdx.x; i < 8192; i += 256)
    if ((i & 3) != 0) acc |= mask[i];
  if (acc) atomicOr(&any, 1);
  __syncthreads();
  if (threadIdx.x == 0) *flag = (any != 0) ? 1 : 0;  // 1 = byte layout
}

// --- prep:
//   efp[f][h]   = exp2( (femb@Ww[:E] + b) * 2log2e )   (so efp*ehp = e^{2x})
//   ehp2[h2][w] = float2( exp2(S*(hemb@Ww[E:])[2h2][w]),
//                         exp2(S*(...)[2h2+1][w]) )    (h-PAIR interleaved)
//   wusum = sum(Wu)
__global__ __launch_bounds__(256) void prep_kernel(
    const float* __restrict__ femb, const float* __restrict__ hemb,
    const float* __restrict__ Ww, const float* __restrict__ bw,
    const float* __restrict__ Wu,
    float* __restrict__ efp, float* __restrict__ ehp2,
    float* __restrict__ wusum) {
  constexpr float S = 2.0f * kLog2e;
  constexpr int NF = Fdim * Hdim;        // 128000
  constexpr int NH2 = (Hdim / 2) * Wdim; // 128000 (one thread per (h-pair, w))
  int idx = blockIdx.x * 256 + threadIdx.x;
  if (idx < NF) {
    int f = idx >> 6, h = idx & 63;
    float acc = bw[h];
#pragma unroll
    for (int e = 0; e < Edim; ++e)
      acc = fmaf(femb[f * Edim + e], Ww[e * Hdim + h], acc);
    efp[idx] = fast_exp2(acc * S);
  } else if (idx < NF + NH2) {
    int j = idx - NF;
    int h2 = j / Wdim, w = j - h2 * Wdim;
    float a0 = 0.f, a1 = 0.f;
#pragma unroll
    for (int e = 0; e < Edim; ++e) {
      float he = hemb[w * Edim + e];
      a0 = fmaf(he, Ww[(Edim + e) * Hdim + 2 * h2 + 0], a0);
      a1 = fmaf(he, Ww[(Edim + e) * Hdim + 2 * h2 + 1], a1);
    }
    ((float2*)ehp2)[h2 * Wdim + w] =
        make_float2(fast_exp2(a0 * S), fast_exp2(a1 * S));
  } else if (idx < NF + NH2 + 64) {
    int l = idx - (NF + NH2);
    float s = Wu[l];
#pragma unroll
    for (int o = 32; o > 0; o >>= 1) s += __shfl_down(s, o, 64);
    if (l == 0) *wusum = s;
  }
}

// --- main: block = (f-tile, w-chunk). Thread owns NW=4 CONSECUTIVE w's.
// h processed in PAIRS under one rcp:
//   wu0/d0 + wu1/d1 = (wu0*d1 + wu1*d0) * rcp(d0*d1),  d = 1 + efp*ehp
// sneg[fi][j] accumulates; sc = mask * exp2(wls - log2e*sneg)
__global__ __launch_bounds__(256) void attn_ctx_kernel(
    const float* __restrict__ efp, const float* __restrict__ ehp2,
    const float* __restrict__ Wu, const float* __restrict__ wusum_p,
    const unsigned char* mask_b, const int* __restrict__ mflag,
    const float* __restrict__ hemb, float* __restrict__ part) {
  const int f0 = blockIdx.x * FTILE;
  const int chunk = blockIdx.y;
  const int tid = threadIdx.x;

  __shared__ float4 s_fpA[Hdim / 2];     // efp[f0..f0+3][2h2]
  __shared__ float4 s_fpB[Hdim / 2];     // efp[f0..f0+3][2h2+1]
  __shared__ float2 s_wu2[Hdim / 2];     // (2Wu[2h2], 2Wu[2h2+1])
  __shared__ float s_red[4][FTILE][20];  // [wave][fi][16 num + den@16]

  if (tid < Hdim / 2) {
    const int h2 = tid;
    float2 p0 = *(const float2*)(efp + (f0 + 0) * Hdim + 2 * h2);
    float2 p1 = *(const float2*)(efp + (f0 + 1) * Hdim + 2 * h2);
    float2 p2 = *(const float2*)(efp + (f0 + 2) * Hdim + 2 * h2);
    float2 p3 = *(const float2*)(efp + (f0 + 3) * Hdim + 2 * h2);
    s_fpA[h2] = make_float4(p0.x, p1.x, p2.x, p3.x);
    s_fpB[h2] = make_float4(p0.y, p1.y, p2.y, p3.y);
    float2 wu = *(const float2*)(Wu + 2 * h2);
    s_wu2[h2] = make_float2(2.0f * wu.x, 2.0f * wu.y);
  }
  __syncthreads();

  const int mbyte = *mflag;
  const float wls = (*wusum_p) * kLog2e;

  const int w0 = chunk * WTILE + tid * NW;
  const bool wok = (w0 < Wdim);           // Wdim%4==0 -> all-or-nothing
  const int wcl = wok ? w0 : (Wdim - NW); // clamped for safe loads

  float sneg[FTILE][NW];
#pragma unroll
  for (int fi = 0; fi < FTILE; ++fi)
#pragma unroll
    for (int j = 0; j < NW; ++j) sneg[fi][j] = 0.f;

  // ---- h-pair main loop: 2 dwordx4 + 2 LDS b128 + 1 LDS b64 per h-pair
#pragma unroll 4
  for (int h2 = 0; h2 < Hdim / 2; ++h2) {
    const float* row = ehp2 + ((size_t)h2 * Wdim + wcl) * 2;
    float4 ea = *(const float4*)(row);      // (e0,e1) for w0, w0+1
    float4 eb = *(const float4*)(row + 4);  // (e0,e1) for w0+2, w0+3
    float4 fpA = s_fpA[h2];
    float4 fpB = s_fpB[h2];
    float2 wu = s_wu2[h2];
    float e0[NW] = {ea.x, ea.z, eb.x, eb.z};
    float e1[NW] = {ea.y, ea.w, eb.y, eb.w};
    float fA[4] = {fpA.x, fpA.y, fpA.z, fpA.w};
    float fB[4] = {fpB.x, fpB.y, fpB.z, fpB.w};
#pragma unroll
    for (int j = 0; j < NW; ++j)
#pragma unroll
      for (int fi = 0; fi < FTILE; ++fi) {
        float d0 = fmaf(fA[fi], e0[j], 1.0f);
        float d1 = fmaf(fB[fi], e1[j], 1.0f);
        float num = fmaf(wu.y, d0, wu.x * d1);
        sneg[fi][j] = fmaf(num, fast_rcp(d0 * d1), sneg[fi][j]);
      }
  }

  // ---- mask bits: one uint (byte layout) / uint4 (int layout) per f-row
  float mbit[FTILE][NW];
  if (mbyte) {
#pragma unroll
    for (int fi = 0; fi < FTILE; ++fi) {
      unsigned int m =
          *(const unsigned int*)(mask_b + (size_t)(f0 + fi) * Wdim + wcl);
#pragma unroll
      for (int j = 0; j < NW; ++j)
        mbit[fi][j] = wok ? (float)((m >> (8 * j)) & 1u) : 0.f;
    }
  } else {
    const int* mask_i = (const int*)mask_b;
#pragma unroll
    for (int fi = 0; fi < FTILE; ++fi) {
      uint4 m4 = *(const uint4*)(mask_i + (size_t)(f0 + fi) * Wdim + wcl);
      unsigned int mm[NW] = {m4.x, m4.y, m4.z, m4.w};
#pragma unroll
      for (int j = 0; j < NW; ++j)
        mbit[fi][j] = (wok && mm[j]) ? 1.f : 0.f;
    }
  }

  // ---- score + context accumulation
  float den[FTILE] = {0.f, 0.f, 0.f, 0.f};
  float4 cacc[FTILE][4];
#pragma unroll
  for (int fi = 0; fi < FTILE; ++fi)
#pragma unroll
    for (int q = 0; q < 4; ++q) cacc[fi][q] = make_float4(0.f, 0.f, 0.f, 0.f);

  const float4* h4 = (const float4*)(hemb + (size_t)wcl * Edim);
#pragma unroll
  for (int j = 0; j < NW; ++j) {
    float4 hr0 = h4[j * 4 + 0], hr1 = h4[j * 4 + 1];
    float4 hr2 = h4[j * 4 + 2], hr3 = h4[j * 4 + 3];
#pragma unroll
    for (int fi = 0; fi < FTILE; ++fi) {
      float sc = fast_exp2(fmaf(sneg[fi][j], -kLog2e, wls)) * mbit[fi][j];
      den[fi] += sc;
      cacc[fi][0] = f4_fma_s(sc, hr0, cacc[fi][0]);
      cacc[fi][1] = f4_fma_s(sc, hr1, cacc[fi][1]);
      cacc[fi][2] = f4_fma_s(sc, hr2, cacc[fi][2]);
      cacc[fi][3] = f4_fma_s(sc, hr3, cacc[fi][3]);
    }
  }

  // ---- DPP in-wave reduction (VALU pipe), lane 63 -> LDS
  const int lane = tid & 63, wv = tid >> 6;
#pragma unroll
  for (int fi = 0; fi < FTILE; ++fi) {
    float d = wave64_sum(den[fi]);
    if (lane == 63) s_red[wv][fi][16] = d;
#pragma unroll
    for (int q = 0; q < 4; ++q) {
      float cx = wave64_sum(cacc[fi][q].x);
      float cy = wave64_sum(cacc[fi][q].y);
      float cz = wave64_sum(cacc[fi][q].z);
      float cw = wave64_sum(cacc[fi][q].w);
      if (lane == 63) {
        s_red[wv][fi][4 * q + 0] = cx;
        s_red[wv][fi][4 * q + 1] = cy;
        s_red[wv][fi][4 * q + 2] = cz;
        s_red[wv][fi][4 * q + 3] = cw;
      }
    }
  }
  __syncthreads();
  if (tid < FTILE * 17) {
    int fi = tid / 17, k = tid % 17;
    float tot = s_red[0][fi][k] + s_red[1][fi][k] + s_red[2][fi][k] +
                s_red[3][fi][k];
    part[((f0 + fi) * WCHUNKS + chunk) * 17 + k] = tot;
  }
}

// --- finalize: ctx[f][e] = sum_c num / sum_c den ---------------------------
__global__ __launch_bounds__(256) void finalize_kernel(
    const float* __restrict__ part, float* __restrict__ ctx) {
  int idx = blockIdx.x * 256 + threadIdx.x;
  if (idx >= Fdim * Edim) return;
  int f = idx >> 4, e = idx & 15;
  const float* p = part + f * WCHUNKS * 17;
  float den = 0.f, num = 0.f;
#pragma unroll
  for (int c = 0; c < WCHUNKS; ++c) {
    den += p[c * 17 + 16];
    num += p[c * 17 + e];
  }
  ctx[idx] = num / den;
}

// --- out[b][e] = sum_f values[b][f] * ctx[f][e] ----------------------------
__global__ __launch_bounds__(256) void out_gemv_kernel(
    const float* __restrict__ values, const float* __restrict__ ctx,
    float* __restrict__ out) {
  const int b = blockIdx.x, tid = threadIdx.x;
  float acc[Edim];
#pragma unroll
  for (int e = 0; e < Edim; ++e) acc[e] = 0.f;
  for (int f = tid; f < Fdim; f += 256) {
    float v = values[b * Fdim + f];
    const float4* c4 = (const float4*)(ctx + f * Edim);
    float4 c0 = c4[0], c1 = c4[1], c2 = c4[2], c3 = c4[3];
    float cr[Edim] = {c0.x, c0.y, c0.z, c0.w, c1.x, c1.y, c1.z, c1.w,
                      c2.x, c2.y, c2.z, c2.w, c3.x, c3.y, c3.z, c3.w};
#pragma unroll
    for (int e = 0; e < Edim; ++e) acc[e] = fmaf(v, cr[e], acc[e]);
  }
  __shared__ float s_red[4][Edim];
  const int lane = tid & 63, wv = tid >> 6;
#pragma unroll
  for (int e = 0; e < Edim; ++e) {
    float a = wave64_sum(acc[e]);
    if (lane == 63) s_red[wv][e] = a;
  }
  __syncthreads();
  if (tid < Edim)
    out[b * Edim + tid] =
        s_red[0][tid] + s_red[1][tid] + s_red[2][tid] + s_red[3][tid];
}

extern "C" void kernel_launch(void* const* d_in, const int* in_sizes, int n_in,
                              void* d_out, int out_size, void* d_ws,
                              size_t ws_size, hipStream_t stream) {
  const float* values = (const float*)d_in[0];
  const float* femb   = (const float*)d_in[1];
  const float* hemb   = (const float*)d_in[2];
  const float* Ww     = (const float*)d_in[3];
  const float* bw     = (const float*)d_in[4];
  const float* Wu     = (const float*)d_in[5];
  const unsigned char* mask = (const unsigned char*)d_in[6];
  float* out = (float*)d_out;

  // workspace (floats): efp[F*H] | ehp2[H*W] | ctx[F*E] | wusum | mflag | part
  float* ws = (float*)d_ws;
  float* efp = ws;                                    // 128000
  float* ehp2 = efp + Fdim * Hdim;                    // 256000
  float* ctx = ehp2 + (size_t)Hdim * Wdim;            // 32000
  float* wusum = ctx + Fdim * Edim;                   // 1
  int* mflag = (int*)(wusum + 1);                     // 1
  float* part = (float*)(mflag + 1);                  // 2000*4*17 = 136000

  detect_mask_kernel<<<dim3(1), dim3(256), 0, stream>>>(mask, mflag);

  constexpr int NTOT = Fdim * Hdim + (Hdim / 2) * Wdim + 64;
  prep_kernel<<<dim3((NTOT + 255) / 256), dim3(256), 0, stream>>>(
      femb, hemb, Ww, bw, Wu, efp, ehp2, wusum);

  attn_ctx_kernel<<<dim3(Fdim / FTILE, WCHUNKS), dim3(256), 0, stream>>>(
      efp, ehp2, Wu, wusum, mask, mflag, hemb, part);

  finalize_kernel<<<dim3((Fdim * Edim + 255) / 256), dim3(256), 0, stream>>>(
      part, ctx);

  out_gemv_kernel<<<dim3(Bdim), dim3(256), 0, stream>>>(values, ctx, out);
}